// Round 2
// baseline (156.431 us; speedup 1.0000x reference)
//
#include <hip/hip_runtime.h>

// SimplePitchEstimator on MI355X (gfx950).
// ac = irfft(rfft(x,512)^2) == linear self-convolution c[n] = sum_m y[m]*y[n-m],
// y = x - mean(x)  (support 318 < 512, no circular wrap). Direct fp32 conv.
//
// Round-2 design:
//  * LDS = 160 rows x 64 frames x 4 B = 40960 B EXACTLY -> 4 blocks/CU ->
//    all 1024 blocks co-resident (grid tail eliminated).
//  * mu folded into LDS at write time (X stores y = x - mu); out-of-range
//    window reads handled by wave-uniform (row >= 0 ? X[..] : 0) select,
//    so no pad rows and no per-FMA subtracts.
//  * aux buffers (sums / pm / best / lag) time-multiplexed into X rows 0-7
//    with barriers (X is dead by reduction time).
//  * work-balanced lag partition: wave s owns J={42,32,22,24} lags starting
//    at N0={40,82,114,136}; m-rounds of 8 -> per-thread FMAs
//    {3696,3840,2992,3840} (critical 3840 vs 5376 before).

#define SR_F    16000.0f
#define HOPSZ   256
#define FPB     64
#define NROWS   160
#define TFRAMES 4096
#define SAMPLES 1048576

template<int N0, int J, int R>
__device__ __forceinline__ void conv_tile(const float* __restrict__ X, int f,
                                          float& best, int& bl) {
    float acc[J];
    #pragma unroll
    for (int j = 0; j < J; ++j) acc[j] = 0.f;

    // window w[t] = y[N0 - 7 + t - 8*r], t = 0..J+6 (before round r)
    float w[J + 7];
    #pragma unroll
    for (int t = 0; t < J + 7; ++t)
        w[t] = X[(N0 - 7 + t) * FPB + f];          // rows >= 33, always valid

    for (int r = 0; r < R; ++r) {
        if (r > 0) {
            // shift window down by 8 rows (up in index), refill bottom 8
            #pragma unroll
            for (int t = J + 6; t >= 8; --t) w[t] = w[t - 8];
            #pragma unroll
            for (int t = 0; t < 8; ++t) {
                const int row = N0 - 8 * r - 7 + t;   // wave-uniform
                w[t] = (row >= 0) ? X[row * FPB + f] : 0.f;
            }
        }
        const int mb = 8 * r;
        float x[8];
        #pragma unroll
        for (int d = 0; d < 8; ++d)
            x[d] = X[(mb + d) * FPB + f];          // rows mb..mb+7 <= 159
        #pragma unroll
        for (int j = 0; j < J; ++j) {
            #pragma unroll
            for (int d = 0; d < 8; ++d)            // m ascending within round
                acc[j] = fmaf(x[d], w[j + 7 - d], acc[j]);
        }
    }

    // local argmax, first-max semantics
    best = -3.4e38f; bl = N0;
    #pragma unroll
    for (int j = 0; j < J; ++j)
        if (acc[j] > best) { best = acc[j]; bl = N0 + j; }
}

__global__ __launch_bounds__(256, 4)
void pitch_kernel(const float* __restrict__ audio, float* __restrict__ out) {
    __shared__ float X[NROWS * FPB];   // 40960 B exactly

    const int tid = threadIdx.x;
    const int s   = tid >> 6;          // wave id
    const int f   = tid & 63;          // frame within block
    const int blk = blockIdx.x;
    const int b   = blk >> 6;          // batch row
    const int t0  = (blk & 63) << 6;   // first frame of block

    // ---- Phase A: load 40 samples of frame f (chunk s), partial sum ----
    const float* g = audio + (size_t)b * SAMPLES + (size_t)(t0 + f) * HOPSZ + s * 40;
    float v[40];
    float ps = 0.f;
    #pragma unroll
    for (int j = 0; j < 10; ++j) {
        float4 q = reinterpret_cast<const float4*>(g)[j];   // 16B-aligned
        v[4*j+0] = q.x; v[4*j+1] = q.y; v[4*j+2] = q.z; v[4*j+3] = q.w;
        ps += q.x + q.y + q.z + q.w;
    }

    // ---- Phase B: block mean via aux rows 0-3 ----
    X[s * 64 + f] = ps;
    __syncthreads();
    const float mu = (X[f] + X[64 + f] + X[128 + f] + X[192 + f]) * (1.0f / 160.0f);
    float pm = 0.f;
    #pragma unroll
    for (int q = 0; q < 40; ++q) pm = fmaxf(pm, fabsf(v[q] - mu));
    __syncthreads();                       // all sum-reads done

    // ---- Phase C: silent-check partial max via aux rows 0-3 ----
    X[s * 64 + f] = pm;
    __syncthreads();
    float mx = 0.f;
    if (s == 0)
        mx = fmaxf(fmaxf(X[f], X[64 + f]), fmaxf(X[128 + f], X[192 + f]));
    __syncthreads();                       // pm-reads done before overwrite

    // ---- Phase D: write centered frames, transposed, lane-stride-1 ----
    #pragma unroll
    for (int q = 0; q < 40; ++q)
        X[(s * 40 + q) * FPB + f] = v[q] - mu;
    __syncthreads();

    // ---- Phase E: balanced conv tiles ----
    float best; int bl;
    if      (s == 0) conv_tile< 40, 42, 11>(X, f, best, bl);
    else if (s == 1) conv_tile< 82, 32, 15>(X, f, best, bl);
    else if (s == 2) conv_tile<114, 22, 17>(X, f, best, bl);
    else             conv_tile<136, 24, 20>(X, f, best, bl);
    __syncthreads();                       // conv done: X now dead

    // ---- Phase F: cross-wave argmax via aux rows 0-7 ----
    X[s * 64 + f] = best;
    reinterpret_cast<int*>(X)[256 + s * 64 + f] = bl;
    __syncthreads();

    if (s == 0) {
        float bv = X[f];
        int   L  = reinterpret_cast<int*>(X)[256 + f];
        #pragma unroll
        for (int c = 1; c < 4; ++c) {
            const float vv = X[c * 64 + f];
            if (vv > bv) { bv = vv; L = reinterpret_cast<int*>(X)[256 + c * 64 + f]; }
        }
        const float pitch = SR_F / (float)L;
        out[(size_t)b * TFRAMES + t0 + f] = (mx < 1e-8f) ? 0.0f : pitch;
    }
}

extern "C" void kernel_launch(void* const* d_in, const int* in_sizes, int n_in,
                              void* d_out, int out_size, void* d_ws, size_t ws_size,
                              hipStream_t stream) {
    const float* audio = (const float*)d_in[0];
    float* out = (float*)d_out;
    pitch_kernel<<<dim3(1024), dim3(256), 0, stream>>>(audio, out);
}

// Round 3
// 118.227 us; speedup vs baseline: 1.3231x; 1.3231x over previous
//
#include <hip/hip_runtime.h>

// SimplePitchEstimator on MI355X (gfx950).
// ac = irfft(rfft(x,512)^2) == linear self-convolution c[n] = sum_m y[m]*y[n-m],
// y = x - mean(x) (support 318 < 512, no wrap). Direct fp32 conv.
//
// Round-3 design:
//  * LDS = 160x64x4B = 40960 B exactly -> 4 blocks/CU -> all 1024 blocks
//    co-resident in one pass (no grid tail). __launch_bounds__(256,4).
//  * Register-safe tiles: J=15 lags x M=4 m-steps -> acc[15]+w[18]+x[4],
//    ~55 VGPR (round 2's J=42 spilled to scratch: 135 MB WRITE_SIZE).
//  * Balance by PAIRING: wave s = lags [40+15s,54+15s] then [145-15s,159-15s];
//    rounds/wave = 54,55,55,54 (triangle pairs to a constant).
//  * Final reduce tie-breaks on smaller lag (lag ranges interleave across waves).

#define SR_F    16000.0f
#define HOPSZ   256
#define FPB     64
#define NROWS   160
#define TFRAMES 4096
#define SAMPLES 1048576

// One J=15 x M=4 tile: lags N0..N0+14, R rounds of 4 m-steps.
// Updates (best, bl) with first-max semantics (caller guarantees lag order).
template<int N0, int R>
__device__ __forceinline__ void conv_tile(const float* __restrict__ X, int f,
                                          float& best, int& bl) {
    float acc[15];
    #pragma unroll
    for (int j = 0; j < 15; ++j) acc[j] = 0.f;

    // w[t] = y[N0 - 3 + t - 4*r] before round r; rows N0-3..N0+14 valid (>=37)
    float w[18];
    #pragma unroll
    for (int t = 0; t < 18; ++t)
        w[t] = X[(N0 - 3 + t) * FPB + f];

    for (int r = 0; r < R; ++r) {
        const int mb = 4 * r;
        float x0 = X[(mb + 0) * FPB + f];
        float x1 = X[(mb + 1) * FPB + f];
        float x2 = X[(mb + 2) * FPB + f];
        float x3 = X[(mb + 3) * FPB + f];
        #pragma unroll
        for (int j = 0; j < 15; ++j) {      // m ascending within round
            acc[j] = fmaf(x0, w[j + 3], acc[j]);
            acc[j] = fmaf(x1, w[j + 2], acc[j]);
            acc[j] = fmaf(x2, w[j + 1], acc[j]);
            acc[j] = fmaf(x3, w[j + 0], acc[j]);
        }
        if (r < R - 1) {
            // slide window: w'[t] = y[N0 - 7 - 4r + t]
            #pragma unroll
            for (int t = 17; t >= 4; --t) w[t] = w[t - 4];
            #pragma unroll
            for (int t = 0; t < 4; ++t) {
                const int row = N0 - 4 * r - 7 + t;        // wave-uniform
                w[t] = (row >= 0) ? X[row * FPB + f] : 0.f; // y[neg] == 0 exact
            }
        }
    }

    #pragma unroll
    for (int j = 0; j < 15; ++j)
        if (acc[j] > best) { best = acc[j]; bl = N0 + j; }  // strict >: first max
}

__global__ __launch_bounds__(256, 4)
void pitch_kernel(const float* __restrict__ audio, float* __restrict__ out) {
    __shared__ float X[NROWS * FPB];   // 40960 B exactly

    const int tid = threadIdx.x;
    const int s   = tid >> 6;          // wave id
    const int f   = tid & 63;          // frame within block
    const int blk = blockIdx.x;
    const int b   = blk >> 6;          // batch row
    const int t0  = (blk & 63) << 6;   // first frame of block

    // ---- Phase A: load 40 samples of frame f (chunk s), partial sum ----
    const float* g = audio + (size_t)b * SAMPLES + (size_t)(t0 + f) * HOPSZ + s * 40;
    float v[40];
    float ps = 0.f;
    #pragma unroll
    for (int j = 0; j < 10; ++j) {
        float4 q = reinterpret_cast<const float4*>(g)[j];   // 16B-aligned
        v[4*j+0] = q.x; v[4*j+1] = q.y; v[4*j+2] = q.z; v[4*j+3] = q.w;
        ps += q.x + q.y + q.z + q.w;
    }

    // ---- Phase B: block mean via aux rows 0-3 ----
    X[s * 64 + f] = ps;
    __syncthreads();
    const float mu = (X[f] + X[64 + f] + X[128 + f] + X[192 + f]) * (1.0f / 160.0f);
    float pm = 0.f;
    #pragma unroll
    for (int q = 0; q < 40; ++q) pm = fmaxf(pm, fabsf(v[q] - mu));
    __syncthreads();                       // sum-reads done

    // ---- Phase C: silent-check partial max via aux rows 0-3 ----
    X[s * 64 + f] = pm;
    __syncthreads();
    float mx = 0.f;
    if (s == 0)
        mx = fmaxf(fmaxf(X[f], X[64 + f]), fmaxf(X[128 + f], X[192 + f]));
    __syncthreads();                       // pm-reads done

    // ---- Phase D: write centered frames, transposed, lane-stride-1 ----
    #pragma unroll
    for (int q = 0; q < 40; ++q)
        X[(s * 40 + q) * FPB + f] = v[q] - mu;
    __syncthreads();

    // ---- Phase E: paired balanced tiles (A: low lags, B: high lags) ----
    float best = -3.4e38f; int bl = 0;
    if      (s == 0) { conv_tile< 40, 14>(X, f, best, bl);   // rounds 14
                       conv_tile<145, 40>(X, f, best, bl); } // +40 = 54
    else if (s == 1) { conv_tile< 55, 18>(X, f, best, bl);
                       conv_tile<130, 37>(X, f, best, bl); } // 55
    else if (s == 2) { conv_tile< 70, 22>(X, f, best, bl);
                       conv_tile<115, 33>(X, f, best, bl); } // 55
    else             { conv_tile< 85, 25>(X, f, best, bl);
                       conv_tile<100, 29>(X, f, best, bl); } // 54
    __syncthreads();                       // conv done: X now dead

    // ---- Phase F: cross-wave argmax via aux rows 0-7 ----
    X[s * 64 + f] = best;
    reinterpret_cast<int*>(X)[256 + s * 64 + f] = bl;
    __syncthreads();

    if (s == 0) {
        float bv = X[f];
        int   L  = reinterpret_cast<int*>(X)[256 + f];
        #pragma unroll
        for (int c = 1; c < 4; ++c) {
            const float vv = X[c * 64 + f];
            const int   lv = reinterpret_cast<int*>(X)[256 + c * 64 + f];
            if (vv > bv || (vv == bv && lv < L)) { bv = vv; L = lv; }
        }
        const float pitch = SR_F / (float)L;
        out[(size_t)b * TFRAMES + t0 + f] = (mx < 1e-8f) ? 0.0f : pitch;
    }
}

extern "C" void kernel_launch(void* const* d_in, const int* in_sizes, int n_in,
                              void* d_out, int out_size, void* d_ws, size_t ws_size,
                              hipStream_t stream) {
    const float* audio = (const float*)d_in[0];
    float* out = (float*)d_out;
    pitch_kernel<<<dim3(1024), dim3(256), 0, stream>>>(audio, out);
}